// Round 1
// baseline (5181.953 us; speedup 1.0000x reference)
//
#include <hip/hip_runtime.h>
#include <hip/hip_bf16.h>
#include <cmath>

#define HSZ 6400
#define G3H 19200
#define TT  12
#define BH  409600     /* 64*HSZ   */
#define TBH 4915200    /* 12*BH    */

typedef __bf16 bf16x8 __attribute__((ext_vector_type(8)));
typedef float  f32x4  __attribute__((ext_vector_type(4)));
typedef unsigned short u16;
typedef u16 u16x8 __attribute__((ext_vector_type(8)));

__device__ __forceinline__ u16 f2bf(float f) {
    unsigned u = __builtin_bit_cast(unsigned, f);
    u += 0x7fffu + ((u >> 16) & 1u);           // RNE
    return (u16)(u >> 16);
}
__device__ __forceinline__ float bf2f(u16 h) {
    unsigned u = ((unsigned)h) << 16;
    return __builtin_bit_cast(float, u);
}
__device__ __forceinline__ bf16x8 ldb8(const u16* p) {
    return __builtin_bit_cast(bf16x8, *reinterpret_cast<const u16x8*>(p));
}
__device__ __forceinline__ f32x4 mfma16(bf16x8 a, bf16x8 b, f32x4 c) {
    return __builtin_amdgcn_mfma_f32_16x16x32_bf16(a, b, c, 0, 0, 0);
}

// ---- fp32 -> bf16 bulk convert (8 elems/thread) ----
__global__ void k_convert(const float* __restrict__ src, u16* __restrict__ dst, int n8) {
    int i = blockIdx.x * blockDim.x + threadIdx.x;
    if (i >= n8) return;
    const float4* s = reinterpret_cast<const float4*>(src) + (size_t)i * 2;
    float4 a = s[0], b = s[1];
    u16x8 r;
    r[0]=f2bf(a.x); r[1]=f2bf(a.y); r[2]=f2bf(a.z); r[3]=f2bf(a.w);
    r[4]=f2bf(b.x); r[5]=f2bf(b.y); r[6]=f2bf(b.z); r[7]=f2bf(b.w);
    *(reinterpret_cast<u16x8*>(dst) + i) = r;
}

// ---- W_ih0 (19200,200) -> padded (19200,224) bf16 ----
__global__ void k_pad_w0(const float* __restrict__ src, u16* __restrict__ dst) {
    int o = blockIdx.x * 256 + threadIdx.x;     // < 19200*224
    int r = o / 224, i = o - r * 224;
    dst[o] = (i < 200) ? f2bf(src[r * 200 + i]) : (u16)0;
}

// ---- inputs (64,12,200) -> x_b[(t*64+b), 224] bf16 padded ----
__global__ void k_pad_x(const float* __restrict__ src, u16* __restrict__ dst) {
    int o = blockIdx.x * 256 + threadIdx.x;     // < 768*224
    int m = o / 224, i = o - m * 224;
    int t = m >> 6, b = m & 63;
    dst[o] = (i < 200) ? f2bf(src[(b * TT + t) * 200 + i]) : (u16)0;
}

// ---- generic C[m,n] = sum_k A[m,k]*B[n,k] + bias[n]; wave = 64x16 tile ----
// grid: (N/64, M/64), 256 thr. A:(M,K) bf16 rowmajor, B:(N,K) bf16 rowmajor, C:(M,19200) f32
__global__ __launch_bounds__(256) void k_gemm(const u16* __restrict__ A, const u16* __restrict__ Bm,
                                              const float* __restrict__ bias, float* __restrict__ C,
                                              int K) {
    int lane = threadIdx.x & 63, wave = threadIdx.x >> 6;
    int n0 = (blockIdx.x * 4 + wave) * 16;
    int m0 = blockIdx.y * 64;
    const u16* ar = A + (size_t)(m0 + (lane & 15)) * K + ((lane >> 4) * 8);
    const u16* br = Bm + (size_t)(n0 + (lane & 15)) * K + ((lane >> 4) * 8);
    f32x4 acc[4];
#pragma unroll
    for (int i = 0; i < 4; i++) acc[i] = {0.f, 0.f, 0.f, 0.f};
    for (int k = 0; k < K; k += 32) {
        bf16x8 bf = ldb8(br + k);
        bf16x8 a0 = ldb8(ar + k);
        bf16x8 a1 = ldb8(ar + 16 * K + k);
        bf16x8 a2 = ldb8(ar + 32 * K + k);
        bf16x8 a3 = ldb8(ar + 48 * K + k);
        acc[0] = mfma16(a0, bf, acc[0]);
        acc[1] = mfma16(a1, bf, acc[1]);
        acc[2] = mfma16(a2, bf, acc[2]);
        acc[3] = mfma16(a3, bf, acc[3]);
    }
    float bv = bias[n0 + (lane & 15)];
    int crow = m0 + (lane >> 4) * 4;
    int ccol = n0 + (lane & 15);
#pragma unroll
    for (int mi = 0; mi < 4; mi++)
#pragma unroll
        for (int i = 0; i < 4; i++)
            C[(size_t)(crow + mi * 16 + i) * G3H + ccol] = acc[mi][i] + bv;
}

// ---- one GRU timestep: gh = hprev @ Whh^T (+bhh), fused gate epilogue ----
// grid: 400 blocks (16 hidden cols each), 256 thr = 4 waves (K split 4x1600)
__global__ __launch_bounds__(256) void k_step(const u16* __restrict__ Whh,
                                              const u16* __restrict__ hprev,
                                              const float* __restrict__ gi,
                                              const float* __restrict__ bhh,
                                              u16* __restrict__ hout,
                                              float* __restrict__ fout,
                                              int has_h) {
    __shared__ float red[4 * 12 * 256];   // 48 KB: [wave][gate*4+mi][16x16]
    int lane = threadIdx.x & 63, wave = threadIdx.x >> 6;
    int j0 = blockIdx.x * 16;
    f32x4 acc[3][4];
#pragma unroll
    for (int g = 0; g < 3; g++)
#pragma unroll
        for (int mi = 0; mi < 4; mi++) acc[g][mi] = {0.f, 0.f, 0.f, 0.f};

    if (has_h) {
        const u16* ar = hprev + (lane & 15) * HSZ + (lane >> 4) * 8 + wave * 1600;
        const u16* br = Whh + (size_t)(j0 + (lane & 15)) * HSZ + (lane >> 4) * 8 + wave * 1600;
        for (int k = 0; k < 1600; k += 32) {
            bf16x8 b0 = ldb8(br + k);
            bf16x8 b1 = ldb8(br + 40960000 + k);   // gate z rows (+H*H)
            bf16x8 b2 = ldb8(br + 81920000 + k);   // gate n rows (+2*H*H)
            bf16x8 a0 = ldb8(ar + k);
            bf16x8 a1 = ldb8(ar + 16 * HSZ + k);
            bf16x8 a2 = ldb8(ar + 32 * HSZ + k);
            bf16x8 a3 = ldb8(ar + 48 * HSZ + k);
            acc[0][0] = mfma16(a0, b0, acc[0][0]);
            acc[0][1] = mfma16(a1, b0, acc[0][1]);
            acc[0][2] = mfma16(a2, b0, acc[0][2]);
            acc[0][3] = mfma16(a3, b0, acc[0][3]);
            acc[1][0] = mfma16(a0, b1, acc[1][0]);
            acc[1][1] = mfma16(a1, b1, acc[1][1]);
            acc[1][2] = mfma16(a2, b1, acc[1][2]);
            acc[1][3] = mfma16(a3, b1, acc[1][3]);
            acc[2][0] = mfma16(a0, b2, acc[2][0]);
            acc[2][1] = mfma16(a1, b2, acc[2][1]);
            acc[2][2] = mfma16(a2, b2, acc[2][2]);
            acc[2][3] = mfma16(a3, b2, acc[2][3]);
        }
    }
    // dump partial accs: C/D layout row=(lane>>4)*4+i, col=lane&15
    {
        int ob = wave * 3072 + ((lane >> 4) * 4) * 16 + (lane & 15);
#pragma unroll
        for (int g = 0; g < 3; g++)
#pragma unroll
            for (int mi = 0; mi < 4; mi++) {
                int o = ob + (g * 4 + mi) * 256;
                red[o +  0] = acc[g][mi][0];
                red[o + 16] = acc[g][mi][1];
                red[o + 32] = acc[g][mi][2];
                red[o + 48] = acc[g][mi][3];
            }
    }
    __syncthreads();
    // reduce 4 K-partials + gate epilogue; 1024 outputs, 4 per thread
#pragma unroll
    for (int p = 0; p < 4; p++) {
        int e = threadIdx.x + p * 256;
        int b = e >> 4, j = e & 15;
        int mi = b >> 4, row = b & 15;
        float gh[3];
#pragma unroll
        for (int g = 0; g < 3; g++) {
            int o = g * 1024 + mi * 256 + row * 16 + j;
            gh[g] = red[o] + red[o + 3072] + red[o + 6144] + red[o + 9216]
                  + bhh[g * HSZ + j0 + j];
        }
        float gir = gi[(size_t)b * G3H + j0 + j];
        float giz = gi[(size_t)b * G3H + HSZ + j0 + j];
        float gin = gi[(size_t)b * G3H + 2 * HSZ + j0 + j];
        float r = 1.f / (1.f + expf(-(gir + gh[0])));
        float z = 1.f / (1.f + expf(-(giz + gh[1])));
        float nn = tanhf(gin + r * gh[2]);
        float hp = has_h ? bf2f(hprev[b * HSZ + j0 + j]) : 0.f;
        float hv = (1.f - z) * nn + z * hp;
        hout[b * HSZ + j0 + j] = f2bf(hv);
        if (fout) fout[b * HSZ + j0 + j] = hv;
    }
}

// ---- hidden-state tail: out[T] = h0_last, out[T+1] = h1_last (copy of out[11]) ----
__global__ void k_tail(const u16* __restrict__ h0last, float* __restrict__ out) {
    int e = blockIdx.x * 256 + threadIdx.x;    // < 409600
    out[TBH + e] = bf2f(h0last[e]);
    out[TBH + BH + e] = out[11 * BH + e];
}

extern "C" void kernel_launch(void* const* d_in, const int* in_sizes, int n_in,
                              void* d_out, int out_size, void* d_ws, size_t ws_size,
                              hipStream_t stream) {
    const float* x    = (const float*)d_in[0];
    const float* Wih0 = (const float*)d_in[1];
    const float* Whh0 = (const float*)d_in[2];
    const float* bih0 = (const float*)d_in[3];
    const float* bhh0 = (const float*)d_in[4];
    const float* Wih1 = (const float*)d_in[5];
    const float* Whh1 = (const float*)d_in[6];
    const float* bih1 = (const float*)d_in[7];
    const float* bhh1 = (const float*)d_in[8];
    float* out = (float*)d_out;
    char* ws = (char*)d_ws;

    u16*   Whh0b = (u16*)(ws);                    // 245,760,000 B
    u16*   Whh1b = (u16*)(ws + 245760000);        // 245,760,000 B
    u16*   Wih1b = (u16*)(ws + 491520000);        // 245,760,000 B
    u16*   Wih0p = (u16*)(ws + 737280000);        //   8,601,600 B
    u16*   xb    = (u16*)(ws + 745881600);        //     344,064 B
    u16*   h0s   = (u16*)(ws + 746225664);        //   9,830,400 B
    u16*   h1s   = (u16*)(ws + 756056064);        //   9,830,400 B
    float* gi    = (float*)(ws + 765886464);      //  58,982,400 B (shared gi0/gi1)
    // total ws use: 824,868,864 B

    k_convert<<<60000, 256, 0, stream>>>(Whh0, Whh0b, 15360000);
    k_convert<<<60000, 256, 0, stream>>>(Whh1, Whh1b, 15360000);
    k_convert<<<60000, 256, 0, stream>>>(Wih1, Wih1b, 15360000);
    k_pad_w0<<<16800, 256, 0, stream>>>(Wih0, Wih0p);
    k_pad_x<<<672, 256, 0, stream>>>(x, xb);

    // gi0 for all t: (768,224)x(19200,224)^T
    k_gemm<<<dim3(300, 12), 256, 0, stream>>>(xb, Wih0p, bih0, gi, 224);

    for (int t = 0; t < 12; t++)
        k_step<<<400, 256, 0, stream>>>(Whh0b,
                                        h0s + (size_t)(t > 0 ? t - 1 : 0) * BH,
                                        gi + (size_t)t * 64 * G3H, bhh0,
                                        h0s + (size_t)t * BH, nullptr, t > 0);

    // gi1 for all t: (768,6400)x(19200,6400)^T
    k_gemm<<<dim3(300, 12), 256, 0, stream>>>(h0s, Wih1b, bih1, gi, 6400);

    for (int t = 0; t < 12; t++)
        k_step<<<400, 256, 0, stream>>>(Whh1b,
                                        h1s + (size_t)(t > 0 ? t - 1 : 0) * BH,
                                        gi + (size_t)t * 64 * G3H, bhh1,
                                        h1s + (size_t)t * BH,
                                        out + (size_t)t * BH, t > 0);

    k_tail<<<1600, 256, 0, stream>>>(h0s + (size_t)11 * BH, out);
}